// Round 9
// baseline (297.046 us; speedup 1.0000x reference)
//
#include <hip/hip_runtime.h>

// ---------------------------------------------------------------------------
// GRACE GCN 2-layer forward, CSR-gather formulation, bf16 intermediates.
//   h1' = (X W1) * dinv      (bf16, pre-scaled by source dinv, MFMA bf16)
//   h2  = prelu(dinv_d*(h1'_d + sum_j h1'_es[j]) + b1)    (bf16)
//   g'  = (h2 W2) * dinv     (bf16, MFMA)
//   out = prelu(dinv_d*(g'_d + sum_j g'_es[j]) + b2)      (f32)
// R8->R9: per-node edge lists SORTED BY SRC in bin_build. All nodes walk
// their lists in ascending src order in rough lockstep -> GPU-wide concurrent
// gather window ~n/deg rows (~1.6 MB, L2-resident) -> a row's ~16 uses
// cluster in time. R8 showed agg at the L2-miss traffic ceiling (188 MB
// FETCH, 3.0 TB/s, MLP-depth had zero effect).
// ---------------------------------------------------------------------------

#define THREADS 256
#define SCAN_CHUNK 1024   // 256 threads x 4 elements
#define NBLK  256         // partition blocks (fixed chunking)
#define BINSH 7           // 128 nodes per bin
#define BINSZ 128
#define KMAX  1024        // max bins (supports n <= 131072)

typedef unsigned short bf16_t;
typedef __attribute__((ext_vector_type(8))) short bf16x8;
typedef __attribute__((ext_vector_type(4))) float f32x4;

__device__ __forceinline__ float bflo(unsigned int w) {
    union { unsigned int u; float f; } v; v.u = w << 16; return v.f;
}
__device__ __forceinline__ float bfhi(unsigned int w) {
    union { unsigned int u; float f; } v; v.u = w & 0xffff0000u; return v.f;
}
__device__ __forceinline__ unsigned int f2bf(float f) {  // RNE
    union { float f; unsigned int u; } v; v.f = f;
    return (v.u + 0x7fffu + ((v.u >> 16) & 1u)) >> 16;
}

// -------------------- pass 1: per-block bin histogram --------------------
__global__ __launch_bounds__(THREADS) void hist_kernel(const int* __restrict__ dst,
                                                       int* __restrict__ hist,
                                                       int e, int K, int chunk) {
    __shared__ int h[KMAX];
    int t = threadIdx.x, b = blockIdx.x;
    for (int i = t; i < K; i += THREADS) h[i] = 0;
    __syncthreads();
    int lo = b * chunk, hi = min(lo + chunk, e);
    for (int i = lo + t; i < hi; i += THREADS) atomicAdd(&h[dst[i] >> BINSH], 1);
    __syncthreads();
    for (int i = t; i < K; i += THREADS) hist[i * NBLK + b] = h[i];  // bin-major
}

// -------------------- exclusive scan over m elements (3 phases) ------------
__global__ void scan_phaseA_kernel(const int* __restrict__ in, int* __restrict__ bsum, int m) {
    __shared__ int sdata[256];
    int base = blockIdx.x * SCAN_CHUNK;
    int t = threadIdx.x;
    int s = 0;
#pragma unroll
    for (int k = 0; k < 4; ++k) {
        int idx = base + t * 4 + k;
        if (idx < m) s += in[idx];
    }
    sdata[t] = s;
    __syncthreads();
    for (int d = 128; d > 0; d >>= 1) {
        if (t < d) sdata[t] += sdata[t + d];
        __syncthreads();
    }
    if (t == 0) bsum[blockIdx.x] = sdata[0];
}

__global__ void scan_phaseB_kernel(int* __restrict__ bsum, int nb) {
    __shared__ int sdata[256];
    __shared__ int carry;
    int t = threadIdx.x;
    if (t == 0) carry = 0;
    __syncthreads();
    for (int base = 0; base < nb; base += 256) {
        int idx = base + t;
        int v = (idx < nb) ? bsum[idx] : 0;
        sdata[t] = v;
        __syncthreads();
        for (int d = 1; d < 256; d <<= 1) {
            int u = (t >= d) ? sdata[t - d] : 0;
            __syncthreads();
            sdata[t] += u;
            __syncthreads();
        }
        int excl = sdata[t] - v + carry;
        if (idx < nb) bsum[idx] = excl;
        int tot = sdata[255];
        __syncthreads();
        if (t == 0) carry += tot;
        __syncthreads();
    }
}

__global__ void scan_phaseC_kernel(const int* __restrict__ in, const int* __restrict__ bsum,
                                   int* __restrict__ outx, int m) {
    __shared__ int sdata[256];
    int base = blockIdx.x * SCAN_CHUNK;
    int t = threadIdx.x;
    int v[4];
    int s = 0;
#pragma unroll
    for (int k = 0; k < 4; ++k) {
        int idx = base + t * 4 + k;
        v[k] = (idx < m) ? in[idx] : 0;
        s += v[k];
    }
    sdata[t] = s;
    __syncthreads();
    for (int d = 1; d < 256; d <<= 1) {
        int u = (t >= d) ? sdata[t - d] : 0;
        __syncthreads();
        sdata[t] += u;
        __syncthreads();
    }
    int run = bsum[blockIdx.x] + sdata[t] - s;  // exclusive base
#pragma unroll
    for (int k = 0; k < 4; ++k) {
        int idx = base + t * 4 + k;
        if (idx < m) { outx[idx] = run; run += v[k]; }
    }
}

// -------------------- pass 2: rank via LDS + scatter to (bin,blk) segment ---
__global__ __launch_bounds__(THREADS) void rank_scatter_kernel(const int* __restrict__ src,
                                                               const int* __restrict__ dst,
                                                               const int* __restrict__ hoff,
                                                               unsigned int* __restrict__ sorted,
                                                               int e, int K, int chunk) {
    __shared__ int cntl[KMAX];
    __shared__ int basel[KMAX];
    int t = threadIdx.x, b = blockIdx.x;
    for (int i = t; i < K; i += THREADS) { cntl[i] = 0; basel[i] = hoff[i * NBLK + b]; }
    __syncthreads();
    int lo = b * chunk, hi = min(lo + chunk, e);
    for (int i = lo + t; i < hi; i += THREADS) {
        int d = dst[i];
        int bin = d >> BINSH;
        int r = atomicAdd(&cntl[bin], 1);
        sorted[basel[bin] + r] = (unsigned int)src[i] | ((unsigned int)(d & (BINSZ - 1)) << 25);
    }
}

// -------------------- pass 3: per-bin counting sort -> exact CSR ------------
// After the dlocal scatter, each node's segment is insertion-sorted by src so
// the agg kernels sweep h in ascending-address lockstep (L2 temporal reuse).
__global__ __launch_bounds__(THREADS) void bin_build_kernel(const unsigned int* __restrict__ sorted,
                                                            const int* __restrict__ hoff,
                                                            float* __restrict__ dinv,
                                                            int* __restrict__ off,
                                                            int* __restrict__ cnt,
                                                            int* __restrict__ es,
                                                            int n, int e, int K) {
    __shared__ int scnt[BINSZ];
    __shared__ int soff[BINSZ];
    int b = blockIdx.x, t = threadIdx.x;
    int base = hoff[b * NBLK];
    int end  = (b + 1 < K) ? hoff[(b + 1) * NBLK] : e;
    int m = end - base;
    if (t < BINSZ) scnt[t] = 0;
    __syncthreads();
    for (int i = t; i < m; i += THREADS) atomicAdd(&scnt[sorted[base + i] >> 25], 1);
    __syncthreads();
    if (t < BINSZ) soff[t] = scnt[t];
    __syncthreads();
    for (int d = 1; d < BINSZ; d <<= 1) {
        int v = (t < BINSZ && t >= d) ? soff[t - d] : 0;
        __syncthreads();
        if (t < BINSZ) soff[t] += v;
        __syncthreads();
    }
    if (t < BINSZ) {
        int ex = soff[t] - scnt[t];     // exclusive
        int node = (b << BINSH) + t;
        if (node < n) {
            off[node]  = base + ex;
            cnt[node]  = scnt[t];
            dinv[node] = rsqrtf((float)(scnt[t] + 1));  // +1 self loop
        }
        soff[t] = ex;                   // local cursor
    }
    __syncthreads();
    for (int i = t; i < m; i += THREADS) {
        unsigned int pk = sorted[base + i];
        int pos = atomicAdd(&soff[pk >> 25], 1);
        es[base + pos] = (int)(pk & 0x01FFFFFFu);
    }
    __syncthreads();
    // per-node insertion sort by src (one thread per node; segments ~16 long,
    // L2-hot since just written)
    if (t < BINSZ) {
        int node = (b << BINSH) + t;
        if (node < n) {
            int c  = scnt[t];
            int st = base + soff[t] - c;   // soff advanced by c during scatter
            for (int i2 = st + 1; i2 < st + c; ++i2) {
                int key = es[i2];
                int j2 = i2 - 1;
                while (j2 >= st && es[j2] > key) { es[j2 + 1] = es[j2]; --j2; }
                es[j2 + 1] = key;
            }
        }
    }
}

// -------------------- W transpose + bf16 convert: WT[c][k] = bf16(W[k][c]) --
__global__ void wt_kernel(const float* __restrict__ W, bf16_t* __restrict__ WT,
                          int Kdim, int C) {
    int tid = blockIdx.x * blockDim.x + threadIdx.x;
    if (tid >= Kdim * C) return;
    int c = tid / Kdim, k = tid % Kdim;          // WT write contiguous in k
    WT[(size_t)c * Kdim + k] = (bf16_t)f2bf(W[(size_t)k * C + c]);
}

// -------------------- MFMA GEMM: H = (X[n,128] @ W[128,OUTC]) * rowscale ----
// 4 waves/block, 16 rows/wave, zero LDS. A-frag: row=lane&15, k=(lane>>4)*8+j
// (contiguous 8 bf16). B-frag from WT[col][k]: col=lane&15, same k range.
// C/D: col=lane&15, row=(lane>>4)*4+reg (m89-verified layout).
template <int OUTC, bool XBF>
__global__ __launch_bounds__(THREADS) void gemm_mfma_kernel(const void* __restrict__ Xv,
                                                            const bf16_t* __restrict__ WT,
                                                            const float* __restrict__ rowscale,
                                                            bf16_t* __restrict__ H, int n) {
    constexpr int CT = OUTC / 16;            // col tiles
    int wid  = (int)threadIdx.x >> 6;
    int lane = (int)threadIdx.x & 63;
    int rbase = blockIdx.x * 64 + wid * 16;
    int col16 = lane & 15;
    int kgrp  = lane >> 4;                   // 0..3

    int rowA = rbase + col16;                // A rows indexed by lane&15
    if (rowA >= n) rowA = n - 1;             // clamp; stores guarded by D rows

    // ---- load A fragments for all 4 K-steps ----
    bf16x8 a[4];
#pragma unroll
    for (int ks = 0; ks < 4; ++ks) {
        int kb = ks * 32 + kgrp * 8;
        if constexpr (XBF) {
            a[ks] = *reinterpret_cast<const bf16x8*>((const bf16_t*)Xv + (size_t)rowA * 128 + kb);
        } else {
            const float* xp = (const float*)Xv + (size_t)rowA * 128 + kb;
            float4 x0 = *reinterpret_cast<const float4*>(xp);
            float4 x1 = *reinterpret_cast<const float4*>(xp + 4);
            bf16x8 t;
            t[0] = (short)f2bf(x0.x); t[1] = (short)f2bf(x0.y);
            t[2] = (short)f2bf(x0.z); t[3] = (short)f2bf(x0.w);
            t[4] = (short)f2bf(x1.x); t[5] = (short)f2bf(x1.y);
            t[6] = (short)f2bf(x1.z); t[7] = (short)f2bf(x1.w);
            a[ks] = t;
        }
    }

    // ---- rowscale for my 4 output rows ----
    int r0 = rbase + kgrp * 4;
    float sc[4];
#pragma unroll
    for (int j = 0; j < 4; ++j) sc[j] = (r0 + j < n) ? rowscale[r0 + j] : 0.f;

    // ---- K-accumulate per col tile ----
#pragma unroll
    for (int ct = 0; ct < CT; ++ct) {
        const bf16_t* wp = WT + (size_t)(ct * 16 + col16) * 128 + kgrp * 8;
        f32x4 acc = {0.f, 0.f, 0.f, 0.f};
#pragma unroll
        for (int ks = 0; ks < 4; ++ks) {
            bf16x8 b = *reinterpret_cast<const bf16x8*>(wp + ks * 32);
            acc = __builtin_amdgcn_mfma_f32_16x16x32_bf16(a[ks], b, acc, 0, 0, 0);
        }
#pragma unroll
        for (int j = 0; j < 4; ++j) {
            int r = r0 + j;
            if (r < n) H[(size_t)r * OUTC + ct * 16 + col16] = (bf16_t)f2bf(acc[j] * sc[j]);
        }
    }
}

// -------------------- CSR aggregate + bias + PReLU (fused, bf16 gather) -----
// out[i,:] = prelu( dinv[i]*(H'[i,:] + sum_j H'[es[j],:]) + b, a )
// Edge lists are src-sorted: gathers sweep H in ascending order GPU-wide.
template <int F, bool OUTBF>
__global__ __launch_bounds__(THREADS) void agg_kernel(const bf16_t* __restrict__ H,
                                                      const float* __restrict__ dinv,
                                                      const int* __restrict__ off,
                                                      const int* __restrict__ cnt,
                                                      const int* __restrict__ es,
                                                      const float* __restrict__ bias,
                                                      const float* __restrict__ a_ptr,
                                                      void* __restrict__ outv, int n) {
    constexpr int TPN = F / 8;                 // threads per node (8 bf16 = 16B each)
    int node = blockIdx.x * (THREADS / TPN) + (int)threadIdx.x / TPN;
    int l8   = (int)threadIdx.x % TPN;
    if (node >= n) return;
    const int fbase = l8 * 8;

    float acc[8];
    {   // self term (H already pre-scaled by dinv[node])
        uint4 v = *reinterpret_cast<const uint4*>(H + (size_t)node * F + fbase);
        acc[0] = bflo(v.x); acc[1] = bfhi(v.x);
        acc[2] = bflo(v.y); acc[3] = bfhi(v.y);
        acc[4] = bflo(v.z); acc[5] = bfhi(v.z);
        acc[6] = bflo(v.w); acc[7] = bfhi(v.w);
    }

    int j0 = off[node];
    int m  = cnt[node];
    int i = 0;
    for (; i + 3 < m; i += 4) {
        int s0 = es[j0 + i], s1 = es[j0 + i + 1], s2 = es[j0 + i + 2], s3 = es[j0 + i + 3];
        uint4 v0 = *reinterpret_cast<const uint4*>(H + (size_t)s0 * F + fbase);
        uint4 v1 = *reinterpret_cast<const uint4*>(H + (size_t)s1 * F + fbase);
        uint4 v2 = *reinterpret_cast<const uint4*>(H + (size_t)s2 * F + fbase);
        uint4 v3 = *reinterpret_cast<const uint4*>(H + (size_t)s3 * F + fbase);
        acc[0] += (bflo(v0.x) + bflo(v1.x)) + (bflo(v2.x) + bflo(v3.x));
        acc[1] += (bfhi(v0.x) + bfhi(v1.x)) + (bfhi(v2.x) + bfhi(v3.x));
        acc[2] += (bflo(v0.y) + bflo(v1.y)) + (bflo(v2.y) + bflo(v3.y));
        acc[3] += (bfhi(v0.y) + bfhi(v1.y)) + (bfhi(v2.y) + bfhi(v3.y));
        acc[4] += (bflo(v0.z) + bflo(v1.z)) + (bflo(v2.z) + bflo(v3.z));
        acc[5] += (bfhi(v0.z) + bfhi(v1.z)) + (bfhi(v2.z) + bfhi(v3.z));
        acc[6] += (bflo(v0.w) + bflo(v1.w)) + (bflo(v2.w) + bflo(v3.w));
        acc[7] += (bfhi(v0.w) + bfhi(v1.w)) + (bfhi(v2.w) + bfhi(v3.w));
    }
    for (; i < m; ++i) {
        int s0 = es[j0 + i];
        uint4 v0 = *reinterpret_cast<const uint4*>(H + (size_t)s0 * F + fbase);
        acc[0] += bflo(v0.x); acc[1] += bfhi(v0.x);
        acc[2] += bflo(v0.y); acc[3] += bfhi(v0.y);
        acc[4] += bflo(v0.z); acc[5] += bfhi(v0.z);
        acc[6] += bflo(v0.w); acc[7] += bfhi(v0.w);
    }

    float di = dinv[node];
    float a  = *a_ptr;
    float4 b0 = *reinterpret_cast<const float4*>(bias + fbase);
    float4 b1 = *reinterpret_cast<const float4*>(bias + fbase + 4);
    float bb[8] = {b0.x, b0.y, b0.z, b0.w, b1.x, b1.y, b1.z, b1.w};
    float o[8];
#pragma unroll
    for (int k = 0; k < 8; ++k) {
        float v = acc[k] * di + bb[k];
        o[k] = v >= 0.f ? v : a * v;
    }

    if constexpr (OUTBF) {
        uint4 w;
        w.x = f2bf(o[0]) | (f2bf(o[1]) << 16);
        w.y = f2bf(o[2]) | (f2bf(o[3]) << 16);
        w.z = f2bf(o[4]) | (f2bf(o[5]) << 16);
        w.w = f2bf(o[6]) | (f2bf(o[7]) << 16);
        *reinterpret_cast<uint4*>((bf16_t*)outv + (size_t)node * F + fbase) = w;
    } else {
        float* op = (float*)outv + (size_t)node * F + fbase;
        *reinterpret_cast<float4*>(op)     = make_float4(o[0], o[1], o[2], o[3]);
        *reinterpret_cast<float4*>(op + 4) = make_float4(o[4], o[5], o[6], o[7]);
    }
}

extern "C" void kernel_launch(void* const* d_in, const int* in_sizes, int n_in,
                              void* d_out, int out_size, void* d_ws, size_t ws_size,
                              hipStream_t stream) {
    const float* x   = (const float*)d_in[0];
    const int*   ei  = (const int*)d_in[1];
    const float* W1  = (const float*)d_in[2];
    const float* b1  = (const float*)d_in[3];
    const float* W2  = (const float*)d_in[4];
    const float* b2  = (const float*)d_in[5];
    const float* a   = (const float*)d_in[6];

    const int IN  = 128;
    const int HID = 128;
    const int OUT = 64;
    const int n = in_sizes[0] / IN;       // 100000
    const int e = in_sizes[1] / 2;        // 1600000
    const int* src = ei;
    const int* dst = ei + e;

    const int K     = (n + BINSZ - 1) >> BINSH;   // 782 bins
    const int chunk = (e + NBLK - 1) / NBLK;      // 6250 edges/block
    const int M     = K * NBLK;                   // ~200k hist entries
    const int nb    = (M + SCAN_CHUNK - 1) / SCAN_CHUNK;

    auto align = [](size_t v) { return (v + 255) / 256 * 256; };
    char* ws = (char*)d_ws;
    size_t o = 0;
    int*          hist   = (int*)(ws + o);          o += align((size_t)M * 4);
    int*          hoff   = (int*)(ws + o);          o += align((size_t)M * 4);
    int*          bsum   = (int*)(ws + o);          o += align((size_t)nb * 4);
    unsigned int* sorted = (unsigned int*)(ws + o); o += align((size_t)e * 4);
    int*          es     = (int*)(ws + o);          o += align((size_t)e * 4);
    float*        dinv   = (float*)(ws + o);        o += align((size_t)n * 4);
    int*          off    = (int*)(ws + o);          o += align((size_t)n * 4);
    int*          cnt    = (int*)(ws + o);          o += align((size_t)n * 4);
    bf16_t*       h1     = (bf16_t*)(ws + o);       o += align((size_t)n * HID * 2);
    bf16_t*       h2     = (bf16_t*)(ws + o);       o += align((size_t)n * HID * 2);
    bf16_t*       g      = (bf16_t*)(ws + o);       o += align((size_t)n * OUT * 2);
    bf16_t*       WT1    = (bf16_t*)(ws + o);       o += align((size_t)IN * HID * 2);
    bf16_t*       WT2    = (bf16_t*)(ws + o);       o += align((size_t)HID * OUT * 2);

    float* out = (float*)d_out;

    // ---- W transposes (independent of CSR chain) ----
    wt_kernel<<<(IN * HID + THREADS - 1) / THREADS, THREADS, 0, stream>>>(W1, WT1, IN, HID);
    wt_kernel<<<(HID * OUT + THREADS - 1) / THREADS, THREADS, 0, stream>>>(W2, WT2, HID, OUT);

    // ---- CSR build: radix partition + per-bin counting sort ----
    hist_kernel<<<NBLK, THREADS, 0, stream>>>(dst, hist, e, K, chunk);
    scan_phaseA_kernel<<<nb, THREADS, 0, stream>>>(hist, bsum, M);
    scan_phaseB_kernel<<<1, THREADS, 0, stream>>>(bsum, nb);
    scan_phaseC_kernel<<<nb, THREADS, 0, stream>>>(hist, bsum, hoff, M);
    rank_scatter_kernel<<<NBLK, THREADS, 0, stream>>>(src, dst, hoff, sorted, e, K, chunk);
    bin_build_kernel<<<K, THREADS, 0, stream>>>(sorted, hoff, dinv, off, cnt, es, n, e, K);

    int gbG = (n + 63) / 64;

    // ---- layer 1 ----
    gemm_mfma_kernel<128, false><<<gbG, THREADS, 0, stream>>>(x, WT1, dinv, h1, n);
    {
        constexpr int NPB = THREADS / (128 / 8);   // 16 nodes/block
        int gb = (n + NPB - 1) / NPB;
        agg_kernel<128, true><<<gb, THREADS, 0, stream>>>(h1, dinv, off, cnt, es, b1, a, h2, n);
    }

    // ---- layer 2 ----
    gemm_mfma_kernel<64, true><<<gbG, THREADS, 0, stream>>>(h2, WT2, dinv, g, n);
    {
        constexpr int NPB = THREADS / (64 / 8);    // 32 nodes/block
        int gb = (n + NPB - 1) / NPB;
        agg_kernel<64, false><<<gb, THREADS, 0, stream>>>(g, dinv, off, cnt, es, b2, a, out, n);
    }

    (void)ws_size; (void)n_in; (void)out_size;
}

// Round 10
// 243.991 us; speedup vs baseline: 1.2174x; 1.2174x over previous
//
#include <hip/hip_runtime.h>

// ---------------------------------------------------------------------------
// GRACE GCN 2-layer forward, CSR-gather formulation, bf16 intermediates.
//   h1' = (X W1) * dinv      (bf16, pre-scaled by source dinv, MFMA bf16)
//   h2  = prelu(dinv_d*(h1'_d + sum_j h1'_es[j]) + b1)    (bf16)
//   g'  = (h2 W2) * dinv     (bf16, MFMA)
//   out = prelu(dinv_d*(g'_d + sum_j g'_es[j]) + b2)      (f32)
// R9->R10: bin_build does the whole per-bin counting sort + per-node src-sort
// entirely in LDS (R9 did the src-sort as a 1-thread/node insertion sort in
// GLOBAL memory: 110us, VALUBusy 4.5%). Packed keys (dlocal<<25|src) sorted
// within a node == sorted by src. Global fallback (unsorted) if bin > LCAP.
// ---------------------------------------------------------------------------

#define THREADS 256
#define SCAN_CHUNK 1024   // 256 threads x 4 elements
#define NBLK  256         // partition blocks (fixed chunking)
#define BINSH 7           // 128 nodes per bin
#define BINSZ 128
#define KMAX  1024        // max bins (supports n <= 131072)
#define LCAP  4096        // LDS capacity (entries) for bin_build fast path

typedef unsigned short bf16_t;
typedef __attribute__((ext_vector_type(8))) short bf16x8;
typedef __attribute__((ext_vector_type(4))) float f32x4;

__device__ __forceinline__ float bflo(unsigned int w) {
    union { unsigned int u; float f; } v; v.u = w << 16; return v.f;
}
__device__ __forceinline__ float bfhi(unsigned int w) {
    union { unsigned int u; float f; } v; v.u = w & 0xffff0000u; return v.f;
}
__device__ __forceinline__ unsigned int f2bf(float f) {  // RNE
    union { float f; unsigned int u; } v; v.f = f;
    return (v.u + 0x7fffu + ((v.u >> 16) & 1u)) >> 16;
}

// -------------------- pass 1: per-block bin histogram --------------------
__global__ __launch_bounds__(THREADS) void hist_kernel(const int* __restrict__ dst,
                                                       int* __restrict__ hist,
                                                       int e, int K, int chunk) {
    __shared__ int h[KMAX];
    int t = threadIdx.x, b = blockIdx.x;
    for (int i = t; i < K; i += THREADS) h[i] = 0;
    __syncthreads();
    int lo = b * chunk, hi = min(lo + chunk, e);
    for (int i = lo + t; i < hi; i += THREADS) atomicAdd(&h[dst[i] >> BINSH], 1);
    __syncthreads();
    for (int i = t; i < K; i += THREADS) hist[i * NBLK + b] = h[i];  // bin-major
}

// -------------------- exclusive scan over m elements (3 phases) ------------
__global__ void scan_phaseA_kernel(const int* __restrict__ in, int* __restrict__ bsum, int m) {
    __shared__ int sdata[256];
    int base = blockIdx.x * SCAN_CHUNK;
    int t = threadIdx.x;
    int s = 0;
#pragma unroll
    for (int k = 0; k < 4; ++k) {
        int idx = base + t * 4 + k;
        if (idx < m) s += in[idx];
    }
    sdata[t] = s;
    __syncthreads();
    for (int d = 128; d > 0; d >>= 1) {
        if (t < d) sdata[t] += sdata[t + d];
        __syncthreads();
    }
    if (t == 0) bsum[blockIdx.x] = sdata[0];
}

__global__ void scan_phaseB_kernel(int* __restrict__ bsum, int nb) {
    __shared__ int sdata[256];
    __shared__ int carry;
    int t = threadIdx.x;
    if (t == 0) carry = 0;
    __syncthreads();
    for (int base = 0; base < nb; base += 256) {
        int idx = base + t;
        int v = (idx < nb) ? bsum[idx] : 0;
        sdata[t] = v;
        __syncthreads();
        for (int d = 1; d < 256; d <<= 1) {
            int u = (t >= d) ? sdata[t - d] : 0;
            __syncthreads();
            sdata[t] += u;
            __syncthreads();
        }
        int excl = sdata[t] - v + carry;
        if (idx < nb) bsum[idx] = excl;
        int tot = sdata[255];
        __syncthreads();
        if (t == 0) carry += tot;
        __syncthreads();
    }
}

__global__ void scan_phaseC_kernel(const int* __restrict__ in, const int* __restrict__ bsum,
                                   int* __restrict__ outx, int m) {
    __shared__ int sdata[256];
    int base = blockIdx.x * SCAN_CHUNK;
    int t = threadIdx.x;
    int v[4];
    int s = 0;
#pragma unroll
    for (int k = 0; k < 4; ++k) {
        int idx = base + t * 4 + k;
        v[k] = (idx < m) ? in[idx] : 0;
        s += v[k];
    }
    sdata[t] = s;
    __syncthreads();
    for (int d = 1; d < 256; d <<= 1) {
        int u = (t >= d) ? sdata[t - d] : 0;
        __syncthreads();
        sdata[t] += u;
        __syncthreads();
    }
    int run = bsum[blockIdx.x] + sdata[t] - s;  // exclusive base
#pragma unroll
    for (int k = 0; k < 4; ++k) {
        int idx = base + t * 4 + k;
        if (idx < m) { outx[idx] = run; run += v[k]; }
    }
}

// -------------------- pass 2: rank via LDS + scatter to (bin,blk) segment ---
__global__ __launch_bounds__(THREADS) void rank_scatter_kernel(const int* __restrict__ src,
                                                               const int* __restrict__ dst,
                                                               const int* __restrict__ hoff,
                                                               unsigned int* __restrict__ sorted,
                                                               int e, int K, int chunk) {
    __shared__ int cntl[KMAX];
    __shared__ int basel[KMAX];
    int t = threadIdx.x, b = blockIdx.x;
    for (int i = t; i < K; i += THREADS) { cntl[i] = 0; basel[i] = hoff[i * NBLK + b]; }
    __syncthreads();
    int lo = b * chunk, hi = min(lo + chunk, e);
    for (int i = lo + t; i < hi; i += THREADS) {
        int d = dst[i];
        int bin = d >> BINSH;
        int r = atomicAdd(&cntl[bin], 1);
        sorted[basel[bin] + r] = (unsigned int)src[i] | ((unsigned int)(d & (BINSZ - 1)) << 25);
    }
}

// -------------------- pass 3: per-bin counting sort -> exact CSR (all-LDS) --
// Fast path (m <= LCAP): stage packed keys in LDS, histogram+scan+scatter in
// LDS, per-node insertion sort in LDS (packed compare == src compare within a
// node), coalesced write-out. Sorted order is a perf hint only; fallback path
// (m > LCAP) produces unsorted-but-correct segments via global scatter.
__global__ __launch_bounds__(THREADS) void bin_build_kernel(const unsigned int* __restrict__ sorted,
                                                            const int* __restrict__ hoff,
                                                            float* __restrict__ dinv,
                                                            int* __restrict__ off,
                                                            int* __restrict__ cnt,
                                                            int* __restrict__ es,
                                                            int n, int e, int K) {
    __shared__ int scnt[BINSZ];
    __shared__ int sex[BINSZ];
    __shared__ int scur[BINSZ];
    __shared__ int sscan[BINSZ];
    __shared__ unsigned int lin[LCAP];
    __shared__ unsigned int lout[LCAP];
    int b = blockIdx.x, t = threadIdx.x;
    int base = hoff[b * NBLK];
    int end  = (b + 1 < K) ? hoff[(b + 1) * NBLK] : e;
    int m = end - base;
    bool fast = (m <= LCAP);
    if (t < BINSZ) scnt[t] = 0;
    __syncthreads();

    if (fast) {
        for (int i = t; i < m; i += THREADS) {
            unsigned int pk = sorted[base + i];
            lin[i] = pk;
            atomicAdd(&scnt[pk >> 25], 1);
        }
    } else {
        for (int i = t; i < m; i += THREADS) atomicAdd(&scnt[sorted[base + i] >> 25], 1);
    }
    __syncthreads();

    // inclusive Hillis-Steele scan over BINSZ counters
    if (t < BINSZ) sscan[t] = scnt[t];
    __syncthreads();
    for (int d = 1; d < BINSZ; d <<= 1) {
        int v = (t < BINSZ && t >= d) ? sscan[t - d] : 0;
        __syncthreads();
        if (t < BINSZ) sscan[t] += v;
        __syncthreads();
    }
    if (t < BINSZ) {
        int ex = sscan[t] - scnt[t];     // exclusive
        sex[t]  = ex;
        scur[t] = ex;
        int node = (b << BINSH) + t;
        if (node < n) {
            off[node]  = base + ex;
            cnt[node]  = scnt[t];
            dinv[node] = rsqrtf((float)(scnt[t] + 1));  // +1 self loop
        }
    }
    __syncthreads();

    if (fast) {
        // LDS counting-scatter
        for (int i = t; i < m; i += THREADS) {
            unsigned int pk = lin[i];
            int pos = atomicAdd(&scur[pk >> 25], 1);
            lout[pos] = pk;
        }
        __syncthreads();
        // per-node insertion sort in LDS (segments ~deg long)
        if (t < BINSZ) {
            int st = sex[t], c = scnt[t];
            for (int i2 = st + 1; i2 < st + c; ++i2) {
                unsigned int key = lout[i2];
                int j2 = i2 - 1;
                while (j2 >= st && lout[j2] > key) { lout[j2 + 1] = lout[j2]; --j2; }
                lout[j2 + 1] = key;
            }
        }
        __syncthreads();
        // coalesced write-out
        for (int i = t; i < m; i += THREADS) es[base + i] = (int)(lout[i] & 0x01FFFFFFu);
    } else {
        // fallback: global scatter, unsorted segments (correct, rare)
        for (int i = t; i < m; i += THREADS) {
            unsigned int pk = sorted[base + i];
            int pos = atomicAdd(&scur[pk >> 25], 1);
            es[base + pos] = (int)(pk & 0x01FFFFFFu);
        }
    }
}

// -------------------- W transpose + bf16 convert: WT[c][k] = bf16(W[k][c]) --
__global__ void wt_kernel(const float* __restrict__ W, bf16_t* __restrict__ WT,
                          int Kdim, int C) {
    int tid = blockIdx.x * blockDim.x + threadIdx.x;
    if (tid >= Kdim * C) return;
    int c = tid / Kdim, k = tid % Kdim;          // WT write contiguous in k
    WT[(size_t)c * Kdim + k] = (bf16_t)f2bf(W[(size_t)k * C + c]);
}

// -------------------- MFMA GEMM: H = (X[n,128] @ W[128,OUTC]) * rowscale ----
// 4 waves/block, 16 rows/wave, zero LDS. A-frag: row=lane&15, k=(lane>>4)*8+j
// (contiguous 8 bf16). B-frag from WT[col][k]: col=lane&15, same k range.
// C/D: col=lane&15, row=(lane>>4)*4+reg (m89-verified layout).
template <int OUTC, bool XBF>
__global__ __launch_bounds__(THREADS) void gemm_mfma_kernel(const void* __restrict__ Xv,
                                                            const bf16_t* __restrict__ WT,
                                                            const float* __restrict__ rowscale,
                                                            bf16_t* __restrict__ H, int n) {
    constexpr int CT = OUTC / 16;            // col tiles
    int wid  = (int)threadIdx.x >> 6;
    int lane = (int)threadIdx.x & 63;
    int rbase = blockIdx.x * 64 + wid * 16;
    int col16 = lane & 15;
    int kgrp  = lane >> 4;                   // 0..3

    int rowA = rbase + col16;                // A rows indexed by lane&15
    if (rowA >= n) rowA = n - 1;             // clamp; stores guarded by D rows

    // ---- load A fragments for all 4 K-steps ----
    bf16x8 a[4];
#pragma unroll
    for (int ks = 0; ks < 4; ++ks) {
        int kb = ks * 32 + kgrp * 8;
        if constexpr (XBF) {
            a[ks] = *reinterpret_cast<const bf16x8*>((const bf16_t*)Xv + (size_t)rowA * 128 + kb);
        } else {
            const float* xp = (const float*)Xv + (size_t)rowA * 128 + kb;
            float4 x0 = *reinterpret_cast<const float4*>(xp);
            float4 x1 = *reinterpret_cast<const float4*>(xp + 4);
            bf16x8 t;
            t[0] = (short)f2bf(x0.x); t[1] = (short)f2bf(x0.y);
            t[2] = (short)f2bf(x0.z); t[3] = (short)f2bf(x0.w);
            t[4] = (short)f2bf(x1.x); t[5] = (short)f2bf(x1.y);
            t[6] = (short)f2bf(x1.z); t[7] = (short)f2bf(x1.w);
            a[ks] = t;
        }
    }

    // ---- rowscale for my 4 output rows ----
    int r0 = rbase + kgrp * 4;
    float sc[4];
#pragma unroll
    for (int j = 0; j < 4; ++j) sc[j] = (r0 + j < n) ? rowscale[r0 + j] : 0.f;

    // ---- K-accumulate per col tile ----
#pragma unroll
    for (int ct = 0; ct < CT; ++ct) {
        const bf16_t* wp = WT + (size_t)(ct * 16 + col16) * 128 + kgrp * 8;
        f32x4 acc = {0.f, 0.f, 0.f, 0.f};
#pragma unroll
        for (int ks = 0; ks < 4; ++ks) {
            bf16x8 b = *reinterpret_cast<const bf16x8*>(wp + ks * 32);
            acc = __builtin_amdgcn_mfma_f32_16x16x32_bf16(a[ks], b, acc, 0, 0, 0);
        }
#pragma unroll
        for (int j = 0; j < 4; ++j) {
            int r = r0 + j;
            if (r < n) H[(size_t)r * OUTC + ct * 16 + col16] = (bf16_t)f2bf(acc[j] * sc[j]);
        }
    }
}

// -------------------- CSR aggregate + bias + PReLU (fused, bf16 gather) -----
// out[i,:] = prelu( dinv[i]*(H'[i,:] + sum_j H'[es[j],:]) + b, a )
// Edge lists are src-sorted: gathers sweep H in ascending order GPU-wide.
template <int F, bool OUTBF>
__global__ __launch_bounds__(THREADS) void agg_kernel(const bf16_t* __restrict__ H,
                                                      const float* __restrict__ dinv,
                                                      const int* __restrict__ off,
                                                      const int* __restrict__ cnt,
                                                      const int* __restrict__ es,
                                                      const float* __restrict__ bias,
                                                      const float* __restrict__ a_ptr,
                                                      void* __restrict__ outv, int n) {
    constexpr int TPN = F / 8;                 // threads per node (8 bf16 = 16B each)
    int node = blockIdx.x * (THREADS / TPN) + (int)threadIdx.x / TPN;
    int l8   = (int)threadIdx.x % TPN;
    if (node >= n) return;
    const int fbase = l8 * 8;

    float acc[8];
    {   // self term (H already pre-scaled by dinv[node])
        uint4 v = *reinterpret_cast<const uint4*>(H + (size_t)node * F + fbase);
        acc[0] = bflo(v.x); acc[1] = bfhi(v.x);
        acc[2] = bflo(v.y); acc[3] = bfhi(v.y);
        acc[4] = bflo(v.z); acc[5] = bfhi(v.z);
        acc[6] = bflo(v.w); acc[7] = bfhi(v.w);
    }

    int j0 = off[node];
    int m  = cnt[node];
    int i = 0;
    for (; i + 3 < m; i += 4) {
        int s0 = es[j0 + i], s1 = es[j0 + i + 1], s2 = es[j0 + i + 2], s3 = es[j0 + i + 3];
        uint4 v0 = *reinterpret_cast<const uint4*>(H + (size_t)s0 * F + fbase);
        uint4 v1 = *reinterpret_cast<const uint4*>(H + (size_t)s1 * F + fbase);
        uint4 v2 = *reinterpret_cast<const uint4*>(H + (size_t)s2 * F + fbase);
        uint4 v3 = *reinterpret_cast<const uint4*>(H + (size_t)s3 * F + fbase);
        acc[0] += (bflo(v0.x) + bflo(v1.x)) + (bflo(v2.x) + bflo(v3.x));
        acc[1] += (bfhi(v0.x) + bfhi(v1.x)) + (bfhi(v2.x) + bfhi(v3.x));
        acc[2] += (bflo(v0.y) + bflo(v1.y)) + (bflo(v2.y) + bflo(v3.y));
        acc[3] += (bfhi(v0.y) + bfhi(v1.y)) + (bfhi(v2.y) + bfhi(v3.y));
        acc[4] += (bflo(v0.z) + bflo(v1.z)) + (bflo(v2.z) + bflo(v3.z));
        acc[5] += (bfhi(v0.z) + bfhi(v1.z)) + (bfhi(v2.z) + bfhi(v3.z));
        acc[6] += (bflo(v0.w) + bflo(v1.w)) + (bflo(v2.w) + bflo(v3.w));
        acc[7] += (bfhi(v0.w) + bfhi(v1.w)) + (bfhi(v2.w) + bfhi(v3.w));
    }
    for (; i < m; ++i) {
        int s0 = es[j0 + i];
        uint4 v0 = *reinterpret_cast<const uint4*>(H + (size_t)s0 * F + fbase);
        acc[0] += bflo(v0.x); acc[1] += bfhi(v0.x);
        acc[2] += bflo(v0.y); acc[3] += bfhi(v0.y);
        acc[4] += bflo(v0.z); acc[5] += bfhi(v0.z);
        acc[6] += bflo(v0.w); acc[7] += bfhi(v0.w);
    }

    float di = dinv[node];
    float a  = *a_ptr;
    float4 b0 = *reinterpret_cast<const float4*>(bias + fbase);
    float4 b1 = *reinterpret_cast<const float4*>(bias + fbase + 4);
    float bb[8] = {b0.x, b0.y, b0.z, b0.w, b1.x, b1.y, b1.z, b1.w};
    float o[8];
#pragma unroll
    for (int k = 0; k < 8; ++k) {
        float v = acc[k] * di + bb[k];
        o[k] = v >= 0.f ? v : a * v;
    }

    if constexpr (OUTBF) {
        uint4 w;
        w.x = f2bf(o[0]) | (f2bf(o[1]) << 16);
        w.y = f2bf(o[2]) | (f2bf(o[3]) << 16);
        w.z = f2bf(o[4]) | (f2bf(o[5]) << 16);
        w.w = f2bf(o[6]) | (f2bf(o[7]) << 16);
        *reinterpret_cast<uint4*>((bf16_t*)outv + (size_t)node * F + fbase) = w;
    } else {
        float* op = (float*)outv + (size_t)node * F + fbase;
        *reinterpret_cast<float4*>(op)     = make_float4(o[0], o[1], o[2], o[3]);
        *reinterpret_cast<float4*>(op + 4) = make_float4(o[4], o[5], o[6], o[7]);
    }
}

extern "C" void kernel_launch(void* const* d_in, const int* in_sizes, int n_in,
                              void* d_out, int out_size, void* d_ws, size_t ws_size,
                              hipStream_t stream) {
    const float* x   = (const float*)d_in[0];
    const int*   ei  = (const int*)d_in[1];
    const float* W1  = (const float*)d_in[2];
    const float* b1  = (const float*)d_in[3];
    const float* W2  = (const float*)d_in[4];
    const float* b2  = (const float*)d_in[5];
    const float* a   = (const float*)d_in[6];

    const int IN  = 128;
    const int HID = 128;
    const int OUT = 64;
    const int n = in_sizes[0] / IN;       // 100000
    const int e = in_sizes[1] / 2;        // 1600000
    const int* src = ei;
    const int* dst = ei + e;

    const int K     = (n + BINSZ - 1) >> BINSH;   // 782 bins
    const int chunk = (e + NBLK - 1) / NBLK;      // 6250 edges/block
    const int M     = K * NBLK;                   // ~200k hist entries
    const int nb    = (M + SCAN_CHUNK - 1) / SCAN_CHUNK;

    auto align = [](size_t v) { return (v + 255) / 256 * 256; };
    char* ws = (char*)d_ws;
    size_t o = 0;
    int*          hist   = (int*)(ws + o);          o += align((size_t)M * 4);
    int*          hoff   = (int*)(ws + o);          o += align((size_t)M * 4);
    int*          bsum   = (int*)(ws + o);          o += align((size_t)nb * 4);
    unsigned int* sorted = (unsigned int*)(ws + o); o += align((size_t)e * 4);
    int*          es     = (int*)(ws + o);          o += align((size_t)e * 4);
    float*        dinv   = (float*)(ws + o);        o += align((size_t)n * 4);
    int*          off    = (int*)(ws + o);          o += align((size_t)n * 4);
    int*          cnt    = (int*)(ws + o);          o += align((size_t)n * 4);
    bf16_t*       h1     = (bf16_t*)(ws + o);       o += align((size_t)n * HID * 2);
    bf16_t*       h2     = (bf16_t*)(ws + o);       o += align((size_t)n * HID * 2);
    bf16_t*       g      = (bf16_t*)(ws + o);       o += align((size_t)n * OUT * 2);
    bf16_t*       WT1    = (bf16_t*)(ws + o);       o += align((size_t)IN * HID * 2);
    bf16_t*       WT2    = (bf16_t*)(ws + o);       o += align((size_t)HID * OUT * 2);

    float* out = (float*)d_out;

    // ---- W transposes (independent of CSR chain) ----
    wt_kernel<<<(IN * HID + THREADS - 1) / THREADS, THREADS, 0, stream>>>(W1, WT1, IN, HID);
    wt_kernel<<<(HID * OUT + THREADS - 1) / THREADS, THREADS, 0, stream>>>(W2, WT2, HID, OUT);

    // ---- CSR build: radix partition + per-bin counting sort ----
    hist_kernel<<<NBLK, THREADS, 0, stream>>>(dst, hist, e, K, chunk);
    scan_phaseA_kernel<<<nb, THREADS, 0, stream>>>(hist, bsum, M);
    scan_phaseB_kernel<<<1, THREADS, 0, stream>>>(bsum, nb);
    scan_phaseC_kernel<<<nb, THREADS, 0, stream>>>(hist, bsum, hoff, M);
    rank_scatter_kernel<<<NBLK, THREADS, 0, stream>>>(src, dst, hoff, sorted, e, K, chunk);
    bin_build_kernel<<<K, THREADS, 0, stream>>>(sorted, hoff, dinv, off, cnt, es, n, e, K);

    int gbG = (n + 63) / 64;

    // ---- layer 1 ----
    gemm_mfma_kernel<128, false><<<gbG, THREADS, 0, stream>>>(x, WT1, dinv, h1, n);
    {
        constexpr int NPB = THREADS / (128 / 8);   // 16 nodes/block
        int gb = (n + NPB - 1) / NPB;
        agg_kernel<128, true><<<gb, THREADS, 0, stream>>>(h1, dinv, off, cnt, es, b1, a, h2, n);
    }

    // ---- layer 2 ----
    gemm_mfma_kernel<64, true><<<gbG, THREADS, 0, stream>>>(h2, WT2, dinv, g, n);
    {
        constexpr int NPB = THREADS / (64 / 8);    // 32 nodes/block
        int gb = (n + NPB - 1) / NPB;
        agg_kernel<64, false><<<gb, THREADS, 0, stream>>>(g, dinv, off, cnt, es, b2, a, out, n);
    }

    (void)ws_size; (void)n_in; (void)out_size;
}

// Round 11
// 211.041 us; speedup vs baseline: 1.4075x; 1.1561x over previous
//
#include <hip/hip_runtime.h>

// ---------------------------------------------------------------------------
// GRACE GCN 2-layer forward, CSR-gather formulation, bf16 intermediates.
//   h1' = (X W1) * dinv      (bf16, planar-split halves, MFMA bf16)
//   h2  = prelu(dinv_d*(h1'_d + sum_j h1'_es[j]) + b1)    (bf16, split halves)
//   g'  = (h2 W2) * dinv     (bf16, MFMA reading split halves)
//   out = prelu(dinv_d*(g'_d + sum_j g'_es[j]) + b2)      (f32)
// R10->R11: (a) src-sort REMOVED (refuted: FETCH 188->183 MB only, blocks
// don't run in lockstep); bin_build reverted to R8's global-scatter version.
// (b) h1/h2 stored as two planar n x 64 halves; layer-1 aggregation runs as
// two passes each over a 12.8 MB working set (was 25.6 MB) to raise the
// random-gather L2 hit rate. All agg dispatches now use the same <64> shape.
// ---------------------------------------------------------------------------

#define THREADS 256
#define SCAN_CHUNK 1024   // 256 threads x 4 elements
#define NBLK  256         // partition blocks (fixed chunking)
#define BINSH 7           // 128 nodes per bin
#define BINSZ 128
#define KMAX  1024        // max bins (supports n <= 131072)

typedef unsigned short bf16_t;
typedef __attribute__((ext_vector_type(8))) short bf16x8;
typedef __attribute__((ext_vector_type(4))) float f32x4;

__device__ __forceinline__ float bflo(unsigned int w) {
    union { unsigned int u; float f; } v; v.u = w << 16; return v.f;
}
__device__ __forceinline__ float bfhi(unsigned int w) {
    union { unsigned int u; float f; } v; v.u = w & 0xffff0000u; return v.f;
}
__device__ __forceinline__ unsigned int f2bf(float f) {  // RNE
    union { float f; unsigned int u; } v; v.f = f;
    return (v.u + 0x7fffu + ((v.u >> 16) & 1u)) >> 16;
}

// -------------------- pass 1: per-block bin histogram --------------------
__global__ __launch_bounds__(THREADS) void hist_kernel(const int* __restrict__ dst,
                                                       int* __restrict__ hist,
                                                       int e, int K, int chunk) {
    __shared__ int h[KMAX];
    int t = threadIdx.x, b = blockIdx.x;
    for (int i = t; i < K; i += THREADS) h[i] = 0;
    __syncthreads();
    int lo = b * chunk, hi = min(lo + chunk, e);
    for (int i = lo + t; i < hi; i += THREADS) atomicAdd(&h[dst[i] >> BINSH], 1);
    __syncthreads();
    for (int i = t; i < K; i += THREADS) hist[i * NBLK + b] = h[i];  // bin-major
}

// -------------------- exclusive scan over m elements (3 phases) ------------
__global__ void scan_phaseA_kernel(const int* __restrict__ in, int* __restrict__ bsum, int m) {
    __shared__ int sdata[256];
    int base = blockIdx.x * SCAN_CHUNK;
    int t = threadIdx.x;
    int s = 0;
#pragma unroll
    for (int k = 0; k < 4; ++k) {
        int idx = base + t * 4 + k;
        if (idx < m) s += in[idx];
    }
    sdata[t] = s;
    __syncthreads();
    for (int d = 128; d > 0; d >>= 1) {
        if (t < d) sdata[t] += sdata[t + d];
        __syncthreads();
    }
    if (t == 0) bsum[blockIdx.x] = sdata[0];
}

__global__ void scan_phaseB_kernel(int* __restrict__ bsum, int nb) {
    __shared__ int sdata[256];
    __shared__ int carry;
    int t = threadIdx.x;
    if (t == 0) carry = 0;
    __syncthreads();
    for (int base = 0; base < nb; base += 256) {
        int idx = base + t;
        int v = (idx < nb) ? bsum[idx] : 0;
        sdata[t] = v;
        __syncthreads();
        for (int d = 1; d < 256; d <<= 1) {
            int u = (t >= d) ? sdata[t - d] : 0;
            __syncthreads();
            sdata[t] += u;
            __syncthreads();
        }
        int excl = sdata[t] - v + carry;
        if (idx < nb) bsum[idx] = excl;
        int tot = sdata[255];
        __syncthreads();
        if (t == 0) carry += tot;
        __syncthreads();
    }
}

__global__ void scan_phaseC_kernel(const int* __restrict__ in, const int* __restrict__ bsum,
                                   int* __restrict__ outx, int m) {
    __shared__ int sdata[256];
    int base = blockIdx.x * SCAN_CHUNK;
    int t = threadIdx.x;
    int v[4];
    int s = 0;
#pragma unroll
    for (int k = 0; k < 4; ++k) {
        int idx = base + t * 4 + k;
        v[k] = (idx < m) ? in[idx] : 0;
        s += v[k];
    }
    sdata[t] = s;
    __syncthreads();
    for (int d = 1; d < 256; d <<= 1) {
        int u = (t >= d) ? sdata[t - d] : 0;
        __syncthreads();
        sdata[t] += u;
        __syncthreads();
    }
    int run = bsum[blockIdx.x] + sdata[t] - s;  // exclusive base
#pragma unroll
    for (int k = 0; k < 4; ++k) {
        int idx = base + t * 4 + k;
        if (idx < m) { outx[idx] = run; run += v[k]; }
    }
}

// -------------------- pass 2: rank via LDS + scatter to (bin,blk) segment ---
__global__ __launch_bounds__(THREADS) void rank_scatter_kernel(const int* __restrict__ src,
                                                               const int* __restrict__ dst,
                                                               const int* __restrict__ hoff,
                                                               unsigned int* __restrict__ sorted,
                                                               int e, int K, int chunk) {
    __shared__ int cntl[KMAX];
    __shared__ int basel[KMAX];
    int t = threadIdx.x, b = blockIdx.x;
    for (int i = t; i < K; i += THREADS) { cntl[i] = 0; basel[i] = hoff[i * NBLK + b]; }
    __syncthreads();
    int lo = b * chunk, hi = min(lo + chunk, e);
    for (int i = lo + t; i < hi; i += THREADS) {
        int d = dst[i];
        int bin = d >> BINSH;
        int r = atomicAdd(&cntl[bin], 1);
        sorted[basel[bin] + r] = (unsigned int)src[i] | ((unsigned int)(d & (BINSZ - 1)) << 25);
    }
}

// -------------------- pass 3: per-bin counting sort -> exact CSR ------------
// (R8 version: global scatter, no src-sort -- sort was refuted in R10)
__global__ __launch_bounds__(THREADS) void bin_build_kernel(const unsigned int* __restrict__ sorted,
                                                            const int* __restrict__ hoff,
                                                            float* __restrict__ dinv,
                                                            int* __restrict__ off,
                                                            int* __restrict__ cnt,
                                                            int* __restrict__ es,
                                                            int n, int e, int K) {
    __shared__ int scnt[BINSZ];
    __shared__ int soff[BINSZ];
    int b = blockIdx.x, t = threadIdx.x;
    int base = hoff[b * NBLK];
    int end  = (b + 1 < K) ? hoff[(b + 1) * NBLK] : e;
    int m = end - base;
    if (t < BINSZ) scnt[t] = 0;
    __syncthreads();
    for (int i = t; i < m; i += THREADS) atomicAdd(&scnt[sorted[base + i] >> 25], 1);
    __syncthreads();
    if (t < BINSZ) soff[t] = scnt[t];
    __syncthreads();
    for (int d = 1; d < BINSZ; d <<= 1) {
        int v = (t < BINSZ && t >= d) ? soff[t - d] : 0;
        __syncthreads();
        if (t < BINSZ) soff[t] += v;
        __syncthreads();
    }
    if (t < BINSZ) {
        int ex = soff[t] - scnt[t];     // exclusive
        int node = (b << BINSH) + t;
        if (node < n) {
            off[node]  = base + ex;
            cnt[node]  = scnt[t];
            dinv[node] = rsqrtf((float)(scnt[t] + 1));  // +1 self loop
        }
        soff[t] = ex;                   // local cursor
    }
    __syncthreads();
    for (int i = t; i < m; i += THREADS) {
        unsigned int pk = sorted[base + i];
        int pos = atomicAdd(&soff[pk >> 25], 1);
        es[base + pos] = (int)(pk & 0x01FFFFFFu);
    }
}

// ---- W transposes (both weights, one dispatch): WT[c][k] = bf16(W[k][c]) ---
__global__ void wt2_kernel(const float* __restrict__ W1, bf16_t* __restrict__ WT1,
                           const float* __restrict__ W2, bf16_t* __restrict__ WT2,
                           int K1, int C1, int K2, int C2) {
    int tid = blockIdx.x * blockDim.x + threadIdx.x;
    int t1 = K1 * C1;
    if (tid < t1) {
        int c = tid / K1, k = tid % K1;
        WT1[(size_t)c * K1 + k] = (bf16_t)f2bf(W1[(size_t)k * C1 + c]);
    } else if (tid < t1 + K2 * C2) {
        int id = tid - t1;
        int c = id / K2, k = id % K2;
        WT2[(size_t)c * K2 + k] = (bf16_t)f2bf(W2[(size_t)k * C2 + c]);
    }
}

// -------------------- MFMA GEMM: H = (X[n,128] @ W[128,OUTC]) * rowscale ----
// 4 waves/block, 16 rows/wave, zero LDS. A-frag: row=lane&15, k=(lane>>4)*8+j.
// XSPLIT: X given as two planar n x 64 bf16 halves (k<64 -> Xv, else Xv2;
// half is compile-time per ks since ks*32+kgrp*8 chunks never cross 64).
// OSPLIT: output written as two planar n x (OUTC/2) halves (ct decides).
template <int OUTC, bool XBF, bool XSPLIT, bool OSPLIT>
__global__ __launch_bounds__(THREADS) void gemm_mfma_kernel(const void* __restrict__ Xv,
                                                            const void* __restrict__ Xv2,
                                                            const bf16_t* __restrict__ WT,
                                                            const float* __restrict__ rowscale,
                                                            bf16_t* __restrict__ H,
                                                            bf16_t* __restrict__ H2, int n) {
    constexpr int CT = OUTC / 16;            // col tiles
    int wid  = (int)threadIdx.x >> 6;
    int lane = (int)threadIdx.x & 63;
    int rbase = blockIdx.x * 64 + wid * 16;
    int col16 = lane & 15;
    int kgrp  = lane >> 4;                   // 0..3

    int rowA = rbase + col16;                // A rows indexed by lane&15
    if (rowA >= n) rowA = n - 1;             // clamp; stores guarded by D rows

    // ---- load A fragments for all 4 K-steps ----
    bf16x8 a[4];
#pragma unroll
    for (int ks = 0; ks < 4; ++ks) {
        int kb = ks * 32 + kgrp * 8;
        if constexpr (XBF) {
            if constexpr (XSPLIT) {
                const bf16_t* xb = (ks < 2) ? (const bf16_t*)Xv : (const bf16_t*)Xv2;
                a[ks] = *reinterpret_cast<const bf16x8*>(xb + (size_t)rowA * 64 + (kb & 63));
            } else {
                a[ks] = *reinterpret_cast<const bf16x8*>((const bf16_t*)Xv + (size_t)rowA * 128 + kb);
            }
        } else {
            const float* xp = (const float*)Xv + (size_t)rowA * 128 + kb;
            float4 x0 = *reinterpret_cast<const float4*>(xp);
            float4 x1 = *reinterpret_cast<const float4*>(xp + 4);
            bf16x8 t;
            t[0] = (short)f2bf(x0.x); t[1] = (short)f2bf(x0.y);
            t[2] = (short)f2bf(x0.z); t[3] = (short)f2bf(x0.w);
            t[4] = (short)f2bf(x1.x); t[5] = (short)f2bf(x1.y);
            t[6] = (short)f2bf(x1.z); t[7] = (short)f2bf(x1.w);
            a[ks] = t;
        }
    }

    // ---- rowscale for my 4 output rows ----
    int r0 = rbase + kgrp * 4;
    float sc[4];
#pragma unroll
    for (int j = 0; j < 4; ++j) sc[j] = (r0 + j < n) ? rowscale[r0 + j] : 0.f;

    // ---- K-accumulate per col tile ----
#pragma unroll
    for (int ct = 0; ct < CT; ++ct) {
        const bf16_t* wp = WT + (size_t)(ct * 16 + col16) * 128 + kgrp * 8;
        f32x4 acc = {0.f, 0.f, 0.f, 0.f};
#pragma unroll
        for (int ks = 0; ks < 4; ++ks) {
            bf16x8 b = *reinterpret_cast<const bf16x8*>(wp + ks * 32);
            acc = __builtin_amdgcn_mfma_f32_16x16x32_bf16(a[ks], b, acc, 0, 0, 0);
        }
#pragma unroll
        for (int j = 0; j < 4; ++j) {
            int r = r0 + j;
            if (r < n) {
                bf16_t val = (bf16_t)f2bf(acc[j] * sc[j]);
                if constexpr (OSPLIT) {
                    if (ct < CT / 2) H [(size_t)r * (OUTC / 2) + ct * 16 + col16] = val;
                    else             H2[(size_t)r * (OUTC / 2) + (ct - CT / 2) * 16 + col16] = val;
                } else {
                    H[(size_t)r * OUTC + ct * 16 + col16] = val;
                }
            }
        }
    }
}

// -------------------- CSR aggregate + bias + PReLU (fused, bf16 gather) -----
// out[i,:] = prelu( dinv[i]*(H'[i,:] + sum_j H'[es[j],:]) + b, a )
template <int F, bool OUTBF>
__global__ __launch_bounds__(THREADS) void agg_kernel(const bf16_t* __restrict__ H,
                                                      const float* __restrict__ dinv,
                                                      const int* __restrict__ off,
                                                      const int* __restrict__ cnt,
                                                      const int* __restrict__ es,
                                                      const float* __restrict__ bias,
                                                      const float* __restrict__ a_ptr,
                                                      void* __restrict__ outv, int n) {
    constexpr int TPN = F / 8;                 // threads per node (8 bf16 = 16B each)
    int node = blockIdx.x * (THREADS / TPN) + (int)threadIdx.x / TPN;
    int l8   = (int)threadIdx.x % TPN;
    if (node >= n) return;
    const int fbase = l8 * 8;

    float acc[8];
    {   // self term (H already pre-scaled by dinv[node])
        uint4 v = *reinterpret_cast<const uint4*>(H + (size_t)node * F + fbase);
        acc[0] = bflo(v.x); acc[1] = bfhi(v.x);
        acc[2] = bflo(v.y); acc[3] = bfhi(v.y);
        acc[4] = bflo(v.z); acc[5] = bfhi(v.z);
        acc[6] = bflo(v.w); acc[7] = bfhi(v.w);
    }

    int j0 = off[node];
    int m  = cnt[node];
    int i = 0;
    for (; i + 3 < m; i += 4) {
        int s0 = es[j0 + i], s1 = es[j0 + i + 1], s2 = es[j0 + i + 2], s3 = es[j0 + i + 3];
        uint4 v0 = *reinterpret_cast<const uint4*>(H + (size_t)s0 * F + fbase);
        uint4 v1 = *reinterpret_cast<const uint4*>(H + (size_t)s1 * F + fbase);
        uint4 v2 = *reinterpret_cast<const uint4*>(H + (size_t)s2 * F + fbase);
        uint4 v3 = *reinterpret_cast<const uint4*>(H + (size_t)s3 * F + fbase);
        acc[0] += (bflo(v0.x) + bflo(v1.x)) + (bflo(v2.x) + bflo(v3.x));
        acc[1] += (bfhi(v0.x) + bfhi(v1.x)) + (bfhi(v2.x) + bfhi(v3.x));
        acc[2] += (bflo(v0.y) + bflo(v1.y)) + (bflo(v2.y) + bflo(v3.y));
        acc[3] += (bfhi(v0.y) + bfhi(v1.y)) + (bfhi(v2.y) + bfhi(v3.y));
        acc[4] += (bflo(v0.z) + bflo(v1.z)) + (bflo(v2.z) + bflo(v3.z));
        acc[5] += (bfhi(v0.z) + bfhi(v1.z)) + (bfhi(v2.z) + bfhi(v3.z));
        acc[6] += (bflo(v0.w) + bflo(v1.w)) + (bflo(v2.w) + bflo(v3.w));
        acc[7] += (bfhi(v0.w) + bfhi(v1.w)) + (bfhi(v2.w) + bfhi(v3.w));
    }
    for (; i < m; ++i) {
        int s0 = es[j0 + i];
        uint4 v0 = *reinterpret_cast<const uint4*>(H + (size_t)s0 * F + fbase);
        acc[0] += bflo(v0.x); acc[1] += bfhi(v0.x);
        acc[2] += bflo(v0.y); acc[3] += bfhi(v0.y);
        acc[4] += bflo(v0.z); acc[5] += bfhi(v0.z);
        acc[6] += bflo(v0.w); acc[7] += bfhi(v0.w);
    }

    float di = dinv[node];
    float a  = *a_ptr;
    float4 b0 = *reinterpret_cast<const float4*>(bias + fbase);
    float4 b1 = *reinterpret_cast<const float4*>(bias + fbase + 4);
    float bb[8] = {b0.x, b0.y, b0.z, b0.w, b1.x, b1.y, b1.z, b1.w};
    float o[8];
#pragma unroll
    for (int k = 0; k < 8; ++k) {
        float v = acc[k] * di + bb[k];
        o[k] = v >= 0.f ? v : a * v;
    }

    if constexpr (OUTBF) {
        uint4 w;
        w.x = f2bf(o[0]) | (f2bf(o[1]) << 16);
        w.y = f2bf(o[2]) | (f2bf(o[3]) << 16);
        w.z = f2bf(o[4]) | (f2bf(o[5]) << 16);
        w.w = f2bf(o[6]) | (f2bf(o[7]) << 16);
        *reinterpret_cast<uint4*>((bf16_t*)outv + (size_t)node * F + fbase) = w;
    } else {
        float* op = (float*)outv + (size_t)node * F + fbase;
        *reinterpret_cast<float4*>(op)     = make_float4(o[0], o[1], o[2], o[3]);
        *reinterpret_cast<float4*>(op + 4) = make_float4(o[4], o[5], o[6], o[7]);
    }
}

extern "C" void kernel_launch(void* const* d_in, const int* in_sizes, int n_in,
                              void* d_out, int out_size, void* d_ws, size_t ws_size,
                              hipStream_t stream) {
    const float* x   = (const float*)d_in[0];
    const int*   ei  = (const int*)d_in[1];
    const float* W1  = (const float*)d_in[2];
    const float* b1  = (const float*)d_in[3];
    const float* W2  = (const float*)d_in[4];
    const float* b2  = (const float*)d_in[5];
    const float* a   = (const float*)d_in[6];

    const int IN  = 128;
    const int HID = 128;
    const int OUT = 64;
    const int n = in_sizes[0] / IN;       // 100000
    const int e = in_sizes[1] / 2;        // 1600000
    const int* src = ei;
    const int* dst = ei + e;

    const int K     = (n + BINSZ - 1) >> BINSH;   // 782 bins
    const int chunk = (e + NBLK - 1) / NBLK;      // 6250 edges/block
    const int M     = K * NBLK;                   // ~200k hist entries
    const int nb    = (M + SCAN_CHUNK - 1) / SCAN_CHUNK;

    auto align = [](size_t v) { return (v + 255) / 256 * 256; };
    char* ws = (char*)d_ws;
    size_t o = 0;
    int*          hist   = (int*)(ws + o);          o += align((size_t)M * 4);
    int*          hoff   = (int*)(ws + o);          o += align((size_t)M * 4);
    int*          bsum   = (int*)(ws + o);          o += align((size_t)nb * 4);
    unsigned int* sorted = (unsigned int*)(ws + o); o += align((size_t)e * 4);
    int*          es     = (int*)(ws + o);          o += align((size_t)e * 4);
    float*        dinv   = (float*)(ws + o);        o += align((size_t)n * 4);
    int*          off    = (int*)(ws + o);          o += align((size_t)n * 4);
    int*          cnt    = (int*)(ws + o);          o += align((size_t)n * 4);
    bf16_t*       h1a    = (bf16_t*)(ws + o);       o += align((size_t)n * 64 * 2);
    bf16_t*       h1b    = (bf16_t*)(ws + o);       o += align((size_t)n * 64 * 2);
    bf16_t*       h2a    = (bf16_t*)(ws + o);       o += align((size_t)n * 64 * 2);
    bf16_t*       h2b    = (bf16_t*)(ws + o);       o += align((size_t)n * 64 * 2);
    bf16_t*       g      = (bf16_t*)(ws + o);       o += align((size_t)n * OUT * 2);
    bf16_t*       WT1    = (bf16_t*)(ws + o);       o += align((size_t)IN * HID * 2);
    bf16_t*       WT2    = (bf16_t*)(ws + o);       o += align((size_t)HID * OUT * 2);

    float* out = (float*)d_out;

    // ---- W transposes (one dispatch, independent of CSR chain) ----
    {
        int tot = IN * HID + HID * OUT;
        wt2_kernel<<<(tot + THREADS - 1) / THREADS, THREADS, 0, stream>>>(
            W1, WT1, W2, WT2, IN, HID, HID, OUT);
    }

    // ---- CSR build: radix partition + per-bin counting sort ----
    hist_kernel<<<NBLK, THREADS, 0, stream>>>(dst, hist, e, K, chunk);
    scan_phaseA_kernel<<<nb, THREADS, 0, stream>>>(hist, bsum, M);
    scan_phaseB_kernel<<<1, THREADS, 0, stream>>>(bsum, nb);
    scan_phaseC_kernel<<<nb, THREADS, 0, stream>>>(hist, bsum, hoff, M);
    rank_scatter_kernel<<<NBLK, THREADS, 0, stream>>>(src, dst, hoff, sorted, e, K, chunk);
    bin_build_kernel<<<K, THREADS, 0, stream>>>(sorted, hoff, dinv, off, cnt, es, n, e, K);

    int gbG = (n + 63) / 64;
    constexpr int NPB = THREADS / (64 / 8);    // 32 nodes/block for agg<64>
    int gbA = (n + NPB - 1) / NPB;

    // ---- layer 1: GEMM -> planar halves; two half-aggregations ----
    gemm_mfma_kernel<128, false, false, true><<<gbG, THREADS, 0, stream>>>(
        x, nullptr, WT1, dinv, h1a, h1b, n);
    agg_kernel<64, true><<<gbA, THREADS, 0, stream>>>(h1a, dinv, off, cnt, es, b1,      a, h2a, n);
    agg_kernel<64, true><<<gbA, THREADS, 0, stream>>>(h1b, dinv, off, cnt, es, b1 + 64, a, h2b, n);

    // ---- layer 2 ----
    gemm_mfma_kernel<64, true, true, false><<<gbG, THREADS, 0, stream>>>(
        h2a, h2b, WT2, dinv, g, nullptr, n);
    agg_kernel<64, false><<<gbA, THREADS, 0, stream>>>(g, dinv, off, cnt, es, b2, a, out, n);

    (void)ws_size; (void)n_in; (void)out_size;
}

// Round 12
// 197.388 us; speedup vs baseline: 1.5049x; 1.0692x over previous
//
#include <hip/hip_runtime.h>

// ---------------------------------------------------------------------------
// GRACE GCN 2-layer forward, CSR-gather formulation, bf16 intermediates.
//   h1' = (X W1) * dinv      (bf16, planar-split halves, MFMA bf16)
//   h2  = prelu(dinv_d*(h1'_d + sum_j h1'_es[j]) + b1)    (bf16, split halves)
//   g'  = (h2 W2) * dinv     (bf16, MFMA reading split halves)
//   out = prelu(dinv_d*(g'_d + sum_j g'_es[j]) + b2)      (f32)
// R11->R12 (GEMM restructure; R11 gemm was latency-bound: 44us/layer both
// layers, MfmaUtil 2.4%, VALUBusy 7%):
//  (a) swapped MFMA operands: D = mfma(W_frag, X_frag) -> lane owns 4
//      consecutive output cols of ONE row -> packed uint2 stores (4x fewer
//      store instrs), single rowscale per acc.
//  (b) 32 rows/wave (2 row-tiles): W frags serve 8 MFMAs each (was 4),
//      16 independent X loads issued up-front per wave.
// ---------------------------------------------------------------------------

#define THREADS 256
#define SCAN_CHUNK 1024   // 256 threads x 4 elements
#define NBLK  256         // partition blocks (fixed chunking)
#define BINSH 7           // 128 nodes per bin
#define BINSZ 128
#define KMAX  1024        // max bins (supports n <= 131072)

typedef unsigned short bf16_t;
typedef __attribute__((ext_vector_type(8))) short bf16x8;
typedef __attribute__((ext_vector_type(4))) float f32x4;

__device__ __forceinline__ float bflo(unsigned int w) {
    union { unsigned int u; float f; } v; v.u = w << 16; return v.f;
}
__device__ __forceinline__ float bfhi(unsigned int w) {
    union { unsigned int u; float f; } v; v.u = w & 0xffff0000u; return v.f;
}
__device__ __forceinline__ unsigned int f2bf(float f) {  // RNE
    union { float f; unsigned int u; } v; v.f = f;
    return (v.u + 0x7fffu + ((v.u >> 16) & 1u)) >> 16;
}

// -------------------- pass 1: per-block bin histogram --------------------
__global__ __launch_bounds__(THREADS) void hist_kernel(const int* __restrict__ dst,
                                                       int* __restrict__ hist,
                                                       int e, int K, int chunk) {
    __shared__ int h[KMAX];
    int t = threadIdx.x, b = blockIdx.x;
    for (int i = t; i < K; i += THREADS) h[i] = 0;
    __syncthreads();
    int lo = b * chunk, hi = min(lo + chunk, e);
    for (int i = lo + t; i < hi; i += THREADS) atomicAdd(&h[dst[i] >> BINSH], 1);
    __syncthreads();
    for (int i = t; i < K; i += THREADS) hist[i * NBLK + b] = h[i];  // bin-major
}

// -------------------- exclusive scan over m elements (3 phases) ------------
__global__ void scan_phaseA_kernel(const int* __restrict__ in, int* __restrict__ bsum, int m) {
    __shared__ int sdata[256];
    int base = blockIdx.x * SCAN_CHUNK;
    int t = threadIdx.x;
    int s = 0;
#pragma unroll
    for (int k = 0; k < 4; ++k) {
        int idx = base + t * 4 + k;
        if (idx < m) s += in[idx];
    }
    sdata[t] = s;
    __syncthreads();
    for (int d = 128; d > 0; d >>= 1) {
        if (t < d) sdata[t] += sdata[t + d];
        __syncthreads();
    }
    if (t == 0) bsum[blockIdx.x] = sdata[0];
}

__global__ void scan_phaseB_kernel(int* __restrict__ bsum, int nb) {
    __shared__ int sdata[256];
    __shared__ int carry;
    int t = threadIdx.x;
    if (t == 0) carry = 0;
    __syncthreads();
    for (int base = 0; base < nb; base += 256) {
        int idx = base + t;
        int v = (idx < nb) ? bsum[idx] : 0;
        sdata[t] = v;
        __syncthreads();
        for (int d = 1; d < 256; d <<= 1) {
            int u = (t >= d) ? sdata[t - d] : 0;
            __syncthreads();
            sdata[t] += u;
            __syncthreads();
        }
        int excl = sdata[t] - v + carry;
        if (idx < nb) bsum[idx] = excl;
        int tot = sdata[255];
        __syncthreads();
        if (t == 0) carry += tot;
        __syncthreads();
    }
}

__global__ void scan_phaseC_kernel(const int* __restrict__ in, const int* __restrict__ bsum,
                                   int* __restrict__ outx, int m) {
    __shared__ int sdata[256];
    int base = blockIdx.x * SCAN_CHUNK;
    int t = threadIdx.x;
    int v[4];
    int s = 0;
#pragma unroll
    for (int k = 0; k < 4; ++k) {
        int idx = base + t * 4 + k;
        v[k] = (idx < m) ? in[idx] : 0;
        s += v[k];
    }
    sdata[t] = s;
    __syncthreads();
    for (int d = 1; d < 256; d <<= 1) {
        int u = (t >= d) ? sdata[t - d] : 0;
        __syncthreads();
        sdata[t] += u;
        __syncthreads();
    }
    int run = bsum[blockIdx.x] + sdata[t] - s;  // exclusive base
#pragma unroll
    for (int k = 0; k < 4; ++k) {
        int idx = base + t * 4 + k;
        if (idx < m) { outx[idx] = run; run += v[k]; }
    }
}

// -------------------- pass 2: rank via LDS + scatter to (bin,blk) segment ---
__global__ __launch_bounds__(THREADS) void rank_scatter_kernel(const int* __restrict__ src,
                                                               const int* __restrict__ dst,
                                                               const int* __restrict__ hoff,
                                                               unsigned int* __restrict__ sorted,
                                                               int e, int K, int chunk) {
    __shared__ int cntl[KMAX];
    __shared__ int basel[KMAX];
    int t = threadIdx.x, b = blockIdx.x;
    for (int i = t; i < K; i += THREADS) { cntl[i] = 0; basel[i] = hoff[i * NBLK + b]; }
    __syncthreads();
    int lo = b * chunk, hi = min(lo + chunk, e);
    for (int i = lo + t; i < hi; i += THREADS) {
        int d = dst[i];
        int bin = d >> BINSH;
        int r = atomicAdd(&cntl[bin], 1);
        sorted[basel[bin] + r] = (unsigned int)src[i] | ((unsigned int)(d & (BINSZ - 1)) << 25);
    }
}

// -------------------- pass 3: per-bin counting sort -> exact CSR ------------
__global__ __launch_bounds__(THREADS) void bin_build_kernel(const unsigned int* __restrict__ sorted,
                                                            const int* __restrict__ hoff,
                                                            float* __restrict__ dinv,
                                                            int* __restrict__ off,
                                                            int* __restrict__ cnt,
                                                            int* __restrict__ es,
                                                            int n, int e, int K) {
    __shared__ int scnt[BINSZ];
    __shared__ int soff[BINSZ];
    int b = blockIdx.x, t = threadIdx.x;
    int base = hoff[b * NBLK];
    int end  = (b + 1 < K) ? hoff[(b + 1) * NBLK] : e;
    int m = end - base;
    if (t < BINSZ) scnt[t] = 0;
    __syncthreads();
    for (int i = t; i < m; i += THREADS) atomicAdd(&scnt[sorted[base + i] >> 25], 1);
    __syncthreads();
    if (t < BINSZ) soff[t] = scnt[t];
    __syncthreads();
    for (int d = 1; d < BINSZ; d <<= 1) {
        int v = (t < BINSZ && t >= d) ? soff[t - d] : 0;
        __syncthreads();
        if (t < BINSZ) soff[t] += v;
        __syncthreads();
    }
    if (t < BINSZ) {
        int ex = soff[t] - scnt[t];     // exclusive
        int node = (b << BINSH) + t;
        if (node < n) {
            off[node]  = base + ex;
            cnt[node]  = scnt[t];
            dinv[node] = rsqrtf((float)(scnt[t] + 1));  // +1 self loop
        }
        soff[t] = ex;                   // local cursor
    }
    __syncthreads();
    for (int i = t; i < m; i += THREADS) {
        unsigned int pk = sorted[base + i];
        int pos = atomicAdd(&soff[pk >> 25], 1);
        es[base + pos] = (int)(pk & 0x01FFFFFFu);
    }
}

// ---- W transposes (both weights, one dispatch): WT[c][k] = bf16(W[k][c]) ---
__global__ void wt2_kernel(const float* __restrict__ W1, bf16_t* __restrict__ WT1,
                           const float* __restrict__ W2, bf16_t* __restrict__ WT2,
                           int K1, int C1, int K2, int C2) {
    int tid = blockIdx.x * blockDim.x + threadIdx.x;
    int t1 = K1 * C1;
    if (tid < t1) {
        int c = tid / K1, k = tid % K1;
        WT1[(size_t)c * K1 + k] = (bf16_t)f2bf(W1[(size_t)k * C1 + c]);
    } else if (tid < t1 + K2 * C2) {
        int id = tid - t1;
        int c = id / K2, k = id % K2;
        WT2[(size_t)c * K2 + k] = (bf16_t)f2bf(W2[(size_t)k * C2 + c]);
    }
}

// -------------------- MFMA GEMM: H = (X[n,128] @ W[128,OUTC]) * rowscale ----
// Swapped operands: D = mfma(A=W_frag, B=X_frag) so D's col index = X row,
// D's row index = output col. Lane holds 4 consecutive output cols (kgrp*4 +
// reg) of row (tile + lane&15) -> packed uint2 stores. 2 row-tiles per wave
// (32 rows), 4 waves/block (128 rows/block).
// XSPLIT: X given as two planar n x 64 bf16 halves; OSPLIT: output written as
// two planar n x (OUTC/2) halves.
template <int OUTC, bool XBF, bool XSPLIT, bool OSPLIT>
__global__ __launch_bounds__(THREADS) void gemm_mfma_kernel(const void* __restrict__ Xv,
                                                            const void* __restrict__ Xv2,
                                                            const bf16_t* __restrict__ WT,
                                                            const float* __restrict__ rowscale,
                                                            bf16_t* __restrict__ H,
                                                            bf16_t* __restrict__ H2, int n) {
    constexpr int CT = OUTC / 16;            // col tiles
    constexpr int RT = 2;                    // row tiles per wave
    int wid  = (int)threadIdx.x >> 6;
    int lane = (int)threadIdx.x & 63;
    int col16 = lane & 15;
    int kgrp  = lane >> 4;                   // 0..3
    int rbase = blockIdx.x * (4 * RT * 16) + wid * (RT * 16);

    // ---- X fragments + rowscale for RT row-tiles (all loads up-front) ----
    int row[RT];
    float sc[RT];
    bf16x8 xf[RT][4];
#pragma unroll
    for (int rt = 0; rt < RT; ++rt) {
        row[rt] = rbase + rt * 16 + col16;
        int rc = row[rt] < n ? row[rt] : (n - 1);   // clamp loads; stores guarded
        sc[rt] = rowscale[rc];
#pragma unroll
        for (int ks = 0; ks < 4; ++ks) {
            int kb = ks * 32 + kgrp * 8;
            if constexpr (XBF) {
                if constexpr (XSPLIT) {
                    const bf16_t* xb = (ks < 2) ? (const bf16_t*)Xv : (const bf16_t*)Xv2;
                    xf[rt][ks] = *reinterpret_cast<const bf16x8*>(xb + (size_t)rc * 64 + (kb & 63));
                } else {
                    xf[rt][ks] = *reinterpret_cast<const bf16x8*>((const bf16_t*)Xv + (size_t)rc * 128 + kb);
                }
            } else {
                const float* xp = (const float*)Xv + (size_t)rc * 128 + kb;
                float4 x0 = *reinterpret_cast<const float4*>(xp);
                float4 x1 = *reinterpret_cast<const float4*>(xp + 4);
                bf16x8 t;
                t[0] = (short)f2bf(x0.x); t[1] = (short)f2bf(x0.y);
                t[2] = (short)f2bf(x0.z); t[3] = (short)f2bf(x0.w);
                t[4] = (short)f2bf(x1.x); t[5] = (short)f2bf(x1.y);
                t[6] = (short)f2bf(x1.z); t[7] = (short)f2bf(x1.w);
                xf[rt][ks] = t;
            }
        }
    }

    // ---- per col-tile: load W frags once, 2 row-tiles of MFMA, packed store -
#pragma unroll
    for (int ct = 0; ct < CT; ++ct) {
        const bf16_t* wp = WT + (size_t)(ct * 16 + col16) * 128 + kgrp * 8;
        bf16x8 wf[4];
#pragma unroll
        for (int ks = 0; ks < 4; ++ks) wf[ks] = *reinterpret_cast<const bf16x8*>(wp + ks * 32);
#pragma unroll
        for (int rt = 0; rt < RT; ++rt) {
            f32x4 acc = {0.f, 0.f, 0.f, 0.f};
#pragma unroll
            for (int ks = 0; ks < 4; ++ks)
                acc = __builtin_amdgcn_mfma_f32_16x16x32_bf16(wf[ks], xf[rt][ks], acc, 0, 0, 0);
            // lane owns out[row[rt]][ct*16 + kgrp*4 + (0..3)]
            if (row[rt] < n) {
                float s = sc[rt];
                uint2 w;
                w.x = f2bf(acc[0] * s) | (f2bf(acc[1] * s) << 16);
                w.y = f2bf(acc[2] * s) | (f2bf(acc[3] * s) << 16);
                if constexpr (OSPLIT) {
                    int half = ct < CT / 2;
                    bf16_t* hb = half ? H : H2;
                    int cc = half ? ct : ct - CT / 2;
                    *reinterpret_cast<uint2*>(hb + (size_t)row[rt] * (OUTC / 2) + cc * 16 + kgrp * 4) = w;
                } else {
                    *reinterpret_cast<uint2*>(H + (size_t)row[rt] * OUTC + ct * 16 + kgrp * 4) = w;
                }
            }
        }
    }
}

// -------------------- CSR aggregate + bias + PReLU (fused, bf16 gather) -----
// out[i,:] = prelu( dinv[i]*(H'[i,:] + sum_j H'[es[j],:]) + b, a )
template <int F, bool OUTBF>
__global__ __launch_bounds__(THREADS) void agg_kernel(const bf16_t* __restrict__ H,
                                                      const float* __restrict__ dinv,
                                                      const int* __restrict__ off,
                                                      const int* __restrict__ cnt,
                                                      const int* __restrict__ es,
                                                      const float* __restrict__ bias,
                                                      const float* __restrict__ a_ptr,
                                                      void* __restrict__ outv, int n) {
    constexpr int TPN = F / 8;                 // threads per node (8 bf16 = 16B each)
    int node = blockIdx.x * (THREADS / TPN) + (int)threadIdx.x / TPN;
    int l8   = (int)threadIdx.x % TPN;
    if (node >= n) return;
    const int fbase = l8 * 8;

    float acc[8];
    {   // self term (H already pre-scaled by dinv[node])
        uint4 v = *reinterpret_cast<const uint4*>(H + (size_t)node * F + fbase);
        acc[0] = bflo(v.x); acc[1] = bfhi(v.x);
        acc[2] = bflo(v.y); acc[3] = bfhi(v.y);
        acc[4] = bflo(v.z); acc[5] = bfhi(v.z);
        acc[6] = bflo(v.w); acc[7] = bfhi(v.w);
    }

    int j0 = off[node];
    int m  = cnt[node];
    int i = 0;
    for (; i + 3 < m; i += 4) {
        int s0 = es[j0 + i], s1 = es[j0 + i + 1], s2 = es[j0 + i + 2], s3 = es[j0 + i + 3];
        uint4 v0 = *reinterpret_cast<const uint4*>(H + (size_t)s0 * F + fbase);
        uint4 v1 = *reinterpret_cast<const uint4*>(H + (size_t)s1 * F + fbase);
        uint4 v2 = *reinterpret_cast<const uint4*>(H + (size_t)s2 * F + fbase);
        uint4 v3 = *reinterpret_cast<const uint4*>(H + (size_t)s3 * F + fbase);
        acc[0] += (bflo(v0.x) + bflo(v1.x)) + (bflo(v2.x) + bflo(v3.x));
        acc[1] += (bfhi(v0.x) + bfhi(v1.x)) + (bfhi(v2.x) + bfhi(v3.x));
        acc[2] += (bflo(v0.y) + bflo(v1.y)) + (bflo(v2.y) + bflo(v3.y));
        acc[3] += (bfhi(v0.y) + bfhi(v1.y)) + (bfhi(v2.y) + bfhi(v3.y));
        acc[4] += (bflo(v0.z) + bflo(v1.z)) + (bflo(v2.z) + bflo(v3.z));
        acc[5] += (bfhi(v0.z) + bfhi(v1.z)) + (bfhi(v2.z) + bfhi(v3.z));
        acc[6] += (bflo(v0.w) + bflo(v1.w)) + (bflo(v2.w) + bflo(v3.w));
        acc[7] += (bfhi(v0.w) + bfhi(v1.w)) + (bfhi(v2.w) + bfhi(v3.w));
    }
    for (; i < m; ++i) {
        int s0 = es[j0 + i];
        uint4 v0 = *reinterpret_cast<const uint4*>(H + (size_t)s0 * F + fbase);
        acc[0] += bflo(v0.x); acc[1] += bfhi(v0.x);
        acc[2] += bflo(v0.y); acc[3] += bfhi(v0.y);
        acc[4] += bflo(v0.z); acc[5] += bfhi(v0.z);
        acc[6] += bflo(v0.w); acc[7] += bfhi(v0.w);
    }

    float di = dinv[node];
    float a  = *a_ptr;
    float4 b0 = *reinterpret_cast<const float4*>(bias + fbase);
    float4 b1 = *reinterpret_cast<const float4*>(bias + fbase + 4);
    float bb[8] = {b0.x, b0.y, b0.z, b0.w, b1.x, b1.y, b1.z, b1.w};
    float o[8];
#pragma unroll
    for (int k = 0; k < 8; ++k) {
        float v = acc[k] * di + bb[k];
        o[k] = v >= 0.f ? v : a * v;
    }

    if constexpr (OUTBF) {
        uint4 w;
        w.x = f2bf(o[0]) | (f2bf(o[1]) << 16);
        w.y = f2bf(o[2]) | (f2bf(o[3]) << 16);
        w.z = f2bf(o[4]) | (f2bf(o[5]) << 16);
        w.w = f2bf(o[6]) | (f2bf(o[7]) << 16);
        *reinterpret_cast<uint4*>((bf16_t*)outv + (size_t)node * F + fbase) = w;
    } else {
        float* op = (float*)outv + (size_t)node * F + fbase;
        *reinterpret_cast<float4*>(op)     = make_float4(o[0], o[1], o[2], o[3]);
        *reinterpret_cast<float4*>(op + 4) = make_float4(o[4], o[5], o[6], o[7]);
    }
}

extern "C" void kernel_launch(void* const* d_in, const int* in_sizes, int n_in,
                              void* d_out, int out_size, void* d_ws, size_t ws_size,
                              hipStream_t stream) {
    const float* x   = (const float*)d_in[0];
    const int*   ei  = (const int*)d_in[1];
    const float* W1  = (const float*)d_in[2];
    const float* b1  = (const float*)d_in[3];
    const float* W2  = (const float*)d_in[4];
    const float* b2  = (const float*)d_in[5];
    const float* a   = (const float*)d_in[6];

    const int IN  = 128;
    const int HID = 128;
    const int OUT = 64;
    const int n = in_sizes[0] / IN;       // 100000
    const int e = in_sizes[1] / 2;        // 1600000
    const int* src = ei;
    const int* dst = ei + e;

    const int K     = (n + BINSZ - 1) >> BINSH;   // 782 bins
    const int chunk = (e + NBLK - 1) / NBLK;      // 6250 edges/block
    const int M     = K * NBLK;                   // ~200k hist entries
    const int nb    = (M + SCAN_CHUNK - 1) / SCAN_CHUNK;

    auto align = [](size_t v) { return (v + 255) / 256 * 256; };
    char* ws = (char*)d_ws;
    size_t o = 0;
    int*          hist   = (int*)(ws + o);          o += align((size_t)M * 4);
    int*          hoff   = (int*)(ws + o);          o += align((size_t)M * 4);
    int*          bsum   = (int*)(ws + o);          o += align((size_t)nb * 4);
    unsigned int* sorted = (unsigned int*)(ws + o); o += align((size_t)e * 4);
    int*          es     = (int*)(ws + o);          o += align((size_t)e * 4);
    float*        dinv   = (float*)(ws + o);        o += align((size_t)n * 4);
    int*          off    = (int*)(ws + o);          o += align((size_t)n * 4);
    int*          cnt    = (int*)(ws + o);          o += align((size_t)n * 4);
    bf16_t*       h1a    = (bf16_t*)(ws + o);       o += align((size_t)n * 64 * 2);
    bf16_t*       h1b    = (bf16_t*)(ws + o);       o += align((size_t)n * 64 * 2);
    bf16_t*       h2a    = (bf16_t*)(ws + o);       o += align((size_t)n * 64 * 2);
    bf16_t*       h2b    = (bf16_t*)(ws + o);       o += align((size_t)n * 64 * 2);
    bf16_t*       g      = (bf16_t*)(ws + o);       o += align((size_t)n * OUT * 2);
    bf16_t*       WT1    = (bf16_t*)(ws + o);       o += align((size_t)IN * HID * 2);
    bf16_t*       WT2    = (bf16_t*)(ws + o);       o += align((size_t)HID * OUT * 2);

    float* out = (float*)d_out;

    // ---- W transposes (one dispatch, independent of CSR chain) ----
    {
        int tot = IN * HID + HID * OUT;
        wt2_kernel<<<(tot + THREADS - 1) / THREADS, THREADS, 0, stream>>>(
            W1, WT1, W2, WT2, IN, HID, HID, OUT);
    }

    // ---- CSR build: radix partition + per-bin counting sort ----
    hist_kernel<<<NBLK, THREADS, 0, stream>>>(dst, hist, e, K, chunk);
    scan_phaseA_kernel<<<nb, THREADS, 0, stream>>>(hist, bsum, M);
    scan_phaseB_kernel<<<1, THREADS, 0, stream>>>(bsum, nb);
    scan_phaseC_kernel<<<nb, THREADS, 0, stream>>>(hist, bsum, hoff, M);
    rank_scatter_kernel<<<NBLK, THREADS, 0, stream>>>(src, dst, hoff, sorted, e, K, chunk);
    bin_build_kernel<<<K, THREADS, 0, stream>>>(sorted, hoff, dinv, off, cnt, es, n, e, K);

    int gbG = (n + 127) / 128;                 // 128 rows/block (4 waves x 32)
    constexpr int NPB = THREADS / (64 / 8);    // 32 nodes/block for agg<64>
    int gbA = (n + NPB - 1) / NPB;

    // ---- layer 1: GEMM -> planar halves; two half-aggregations ----
    gemm_mfma_kernel<128, false, false, true><<<gbG, THREADS, 0, stream>>>(
        x, nullptr, WT1, dinv, h1a, h1b, n);
    agg_kernel<64, true><<<gbA, THREADS, 0, stream>>>(h1a, dinv, off, cnt, es, b1,      a, h2a, n);
    agg_kernel<64, true><<<gbA, THREADS, 0, stream>>>(h1b, dinv, off, cnt, es, b1 + 64, a, h2b, n);

    // ---- layer 2 ----
    gemm_mfma_kernel<64, true, true, false><<<gbG, THREADS, 0, stream>>>(
        h2a, h2b, WT2, dinv, g, nullptr, n);
    agg_kernel<64, false><<<gbA, THREADS, 0, stream>>>(g, dinv, off, cnt, es, b2, a, out, n);

    (void)ws_size; (void)n_in; (void)out_size;
}